// Round 7
// baseline (164.380 us; speedup 1.0000x reference)
//
#include <hip/hip_runtime.h>
#include <hip/hip_bf16.h>
#include <cstddef>
#include <cstdint>

#define B_ 2
#define S_ 2048
#define E_ 1024
#define H_ 16
#define D_ 64
#define WIN_ 3

using bf16x8 = __attribute__((ext_vector_type(8))) short;  // 8 bf16 = 4 VGPRs
using f32x4  = __attribute__((ext_vector_type(4))) float;  // MFMA C/D
using uintx2 = __attribute__((ext_vector_type(2))) unsigned int;

static __device__ __forceinline__ unsigned short f2bf(float f) {
    union { float f; unsigned int u; } c; c.f = f;
    unsigned int r = c.u + 0x7FFF + ((c.u >> 16) & 1);   // round-to-nearest-even
    return (unsigned short)(r >> 16);
}

static __device__ __forceinline__ void gload16(const void* g, void* l) {
    __builtin_amdgcn_global_load_lds(
        (const __attribute__((address_space(1))) void*)g,
        (__attribute__((address_space(3))) void*)l, 16, 0, 0);
}

static __device__ __forceinline__ unsigned int cvt_pk_bf16(float a, float b) {
    unsigned int d;
    asm("v_cvt_pk_bf16_f32 %0, %1, %2" : "=v"(d) : "v"(a), "v"(b));
    return d;  // lo half = bf16(a), hi half = bf16(b)
}

// XOR-swizzled LDS index (shorts) for [row][chunk-of-8-shorts] tiles with
// 64-short rows: slot = chunk ^ (row & 7). Breaks the 128B-row bank aliasing
// while staying global_load_lds-compatible (lane*16B contiguous).
#define SWZ(row, c) ((((row) * 8) + ((c) ^ ((row) & 7))) * 8)

// ---------------------------------------------------------------------------
// fp32 -> bf16 cast: y=0: x (4M elems), y=1..3: Wq/Wk/Wv (1M each)
// ---------------------------------------------------------------------------
__global__ __launch_bounds__(256) void cast_kernel(
    const float* __restrict__ X,  const float* __restrict__ Wq,
    const float* __restrict__ Wk, const float* __restrict__ Wv,
    unsigned short* __restrict__ xb,  unsigned short* __restrict__ wqb,
    unsigned short* __restrict__ wkb, unsigned short* __restrict__ wvb)
{
    const float* src; unsigned short* dst; int n;
    switch (blockIdx.y) {
        case 0:  src = X;  dst = xb;  n = B_ * S_ * E_; break;
        case 1:  src = Wq; dst = wqb; n = E_ * E_;      break;
        case 2:  src = Wk; dst = wkb; n = E_ * E_;      break;
        default: src = Wv; dst = wvb; n = E_ * E_;      break;
    }
    int i = (blockIdx.x * 256 + threadIdx.x) * 8;
    if (i >= n) return;
    float4 a = *(const float4*)(src + i);
    float4 b = *(const float4*)(src + i + 4);
    ushort4 lo, hi;
    lo.x = f2bf(a.x); lo.y = f2bf(a.y); lo.z = f2bf(a.z); lo.w = f2bf(a.w);
    hi.x = f2bf(b.x); hi.y = f2bf(b.y); hi.z = f2bf(b.z); hi.w = f2bf(b.w);
    *(ushort4*)(dst + i)     = lo;
    *(ushort4*)(dst + i + 4) = hi;
}

// ---------------------------------------------------------------------------
// bf16 MFMA projection GEMM (m97 structure + swizzled LDS):
// C[i,j] = sum_k A[i,k]*B[j,k]; 128x128 tile, BK=64, 4 waves, 4x4 frags.
// z=0: A=x, B=Wq -> q bf16 [B,H,S,D] scaled log2(e)/8 (exp2 softmax path)
// z=1: A=x, B=Wk -> k bf16 [B,H,S,D]
// z=2: A=Wv, B=x (swapped) -> v bf16 in FRAGMENT-NATIVE layout
//      [bh][s/32][d=64][s%32]  (R15): the attn V B-frag read
//      (lane(l15,quad) -> d*32 + quad*8 shorts) becomes a fully
//      contiguous 1KB/instruction global load -> V needs no LDS at all.
//
// XCD tiling (R14, kept): bijective 8x12 rectangles; A+B panels L2-resident.
// ---------------------------------------------------------------------------
__global__ __launch_bounds__(256, 4) void gemm_kernel(
    const unsigned short* __restrict__ xb,
    const unsigned short* __restrict__ wqb, const unsigned short* __restrict__ wkb,
    const unsigned short* __restrict__ wvb,
    const float* __restrict__ bq, const float* __restrict__ bk,
    const float* __restrict__ bv,
    unsigned short* __restrict__ qb, unsigned short* __restrict__ kb,
    unsigned short* __restrict__ vb)
{
    constexpr int BM = 128, BK = 64;
    __shared__ unsigned short As[BM * BK];
    __shared__ unsigned short Bs[BM * BK];

    const int t    = threadIdx.x;
    const int lane = t & 63;
    const int w    = t >> 6;
    const int l15  = lane & 15;
    const int quad = lane >> 4;
    const int wm   = w & 1;
    const int wn   = w >> 1;

    // --- XCD-tiled work assignment (bijective over 768 blocks) ---
    const int l   = blockIdx.x + (blockIdx.y << 5) + (blockIdx.z << 8);
    const int ix  = l & 7;          // XCD id (hw round-robin)
    const int p   = l >> 3;         // position within XCD's 96-block share
    const int x2  = (ix & 3) * 8 + (p & 7);         // m-block 0..31
    const int yz  = (ix >> 2) * 12 + (p >> 3);      // (n,z) 0..23
    const int m0  = x2 * BM;
    const int n0  = (yz & 7) * BM;
    const int z   = yz >> 3;

    const unsigned short *Ab, *Bb; const float* bias; unsigned short* outp;
    int i0, j0; float sc = 1.0f;
    if (z == 0)      { Ab = xb;  Bb = wqb; bias = bq; outp = qb; i0 = m0; j0 = n0;
                       sc = 0.125f * 1.44269504088896f; }
    else if (z == 1) { Ab = xb;  Bb = wkb; bias = bk; outp = kb; i0 = m0; j0 = n0; }
    else             { Ab = wvb; Bb = xb;  bias = bv; outp = vb; i0 = n0; j0 = m0; }

    const int lrow = lane >> 3;
    const int gch  = ((lane & 7) ^ (lrow & 7)) * 8;
    const int lsl  = (lane & 7) * 8;

    f32x4 acc[4][4];
    #pragma unroll
    for (int mt = 0; mt < 4; ++mt)
        #pragma unroll
        for (int nt = 0; nt < 4; ++nt)
            #pragma unroll
            for (int r = 0; r < 4; ++r) acc[mt][nt][r] = 0.f;

    for (int k0 = 0; k0 < E_; k0 += BK) {
        __syncthreads();
        #pragma unroll
        for (int is = 0; is < 4; ++is) {
            int r = (w * 4 + is) * 8 + lrow;
            gload16(Ab + (size_t)(i0 + r) * E_ + k0 + gch, &As[r * BK + lsl]);
            gload16(Bb + (size_t)(j0 + r) * E_ + k0 + gch, &Bs[r * BK + lsl]);
        }
        __syncthreads();

        #pragma unroll
        for (int ks = 0; ks < 2; ++ks) {
            bf16x8 af[4], bfr[4];
            #pragma unroll
            for (int mt = 0; mt < 4; ++mt)
                af[mt] = *(const bf16x8*)&As[SWZ(wm*64 + mt*16 + l15, ks*4 + quad)];
            #pragma unroll
            for (int nt = 0; nt < 4; ++nt)
                bfr[nt] = *(const bf16x8*)&Bs[SWZ(wn*64 + nt*16 + l15, ks*4 + quad)];
            #pragma unroll
            for (int mt = 0; mt < 4; ++mt)
                #pragma unroll
                for (int nt = 0; nt < 4; ++nt)
                    acc[mt][nt] = __builtin_amdgcn_mfma_f32_16x16x32_bf16(
                        af[mt], bfr[nt], acc[mt][nt], 0, 0, 0);
        }
    }

    if (z < 2) {
        float bj[4];
        #pragma unroll
        for (int nt = 0; nt < 4; ++nt) bj[nt] = bias[j0 + wn*64 + nt*16 + l15];
        #pragma unroll
        for (int mt = 0; mt < 4; ++mt) {
            #pragma unroll
            for (int r = 0; r < 4; ++r) {
                int i = i0 + wm*64 + mt*16 + quad*4 + r;
                int b = i >> 11, s = i & (S_ - 1);
                #pragma unroll
                for (int nt = 0; nt < 4; ++nt) {
                    int jj = j0 + wn*64 + nt*16 + l15;
                    int hh = jj >> 6, d = jj & 63;
                    outp[(((size_t)(b * H_ + hh) * S_) + s) * D_ + d] =
                        f2bf((acc[mt][nt][r] + bj[nt]) * sc);
                }
            }
        }
    } else {
        // V store in fragment-native layout [bh][s/32][64][s%32]:
        // elem = ((bh*64 + (s>>5))*64 + d)*32 + (s&31)
        #pragma unroll
        for (int mt = 0; mt < 4; ++mt) {
            #pragma unroll
            for (int r = 0; r < 4; ++r) {
                int i = i0 + wm*64 + mt*16 + quad*4 + r;
                int hh = i >> 6, d = i & 63;
                float bi = bias[i];
                #pragma unroll
                for (int nt = 0; nt < 4; ++nt) {
                    int jj = j0 + wn*64 + nt*16 + l15;
                    int b = jj >> 11, s = jj & (S_ - 1);
                    outp[(((size_t)((b * H_ + hh) * (S_/32) + (s >> 5)) * D_ + d)
                          * 32) + (s & 31)] =
                        f2bf(acc[mt][nt][r] + bi);
                }
            }
        }
    }
}

// ---------------------------------------------------------------------------
// MFMA attention, R15: R9/R14 skeleton; V reads go L2-direct via the
// fragment-native V layout -- V leaves LDS entirely.
//
// R13 failed because V frag loads from [d][s] were lane-strided by 4KB
// (64 cache lines/load). The producer now emits [s/32][d][s%32], so the
// same frag read is one contiguous 1KB transaction. K stays LDS-staged
// (QK is the latency-critical chain -- R10's lesson).
//
// Effects: LDS 66->33.3KB (K dbuf + Dex) -> up to 4 blocks/CU (was 2);
// LDS-read pipe per block-iter halves (1536->768 cy); staging is 2
// gload16/thread (was 4). V issue schedule = R13's proven split (ks=0
// batch before exp/pack, ks=1 after pack; compiled 64 VGPR, no spill).
// Per-XCD V working set 1MB -> L2-resident via bh swizzle.
// Spill guard: WRITE_SIZE (~16MB good, ~500MB = spill).
// q pre-scaled by log2(e)/8 in gemm -> raw v_exp2_f32 here.
// XCD swizzle: bh = (j&7)*4 + (j>>7) keeps each XCD on 4 bh (L2-resident).
// ---------------------------------------------------------------------------
__global__ __launch_bounds__(512, 4) void attn_kernel(
    const unsigned short* __restrict__ Q, const unsigned short* __restrict__ K,
    const unsigned short* __restrict__ V, float* __restrict__ out)
{
    constexpr int TQ = 128, TK = 128;
    // per buffer (8192 shorts = 16KB): Ks0 @0 (keys 0..63), Ks1 @4096 (64..127)
    __shared__ unsigned short KV[2][8192];
    __shared__ float          Dex[TQ];

    const int t    = threadIdx.x;
    const int lane = t & 63;
    const int w    = t >> 6;        // wave 0..7
    const int wq   = w & 3;         // q-group (32 rows)
    const int wk   = w >> 2;        // key half
    const int l15  = lane & 15;
    const int quad = lane >> 4;

    const int j    = blockIdx.x;
    const int bh   = (j & 7) * 4 + (j >> 7);
    const int q0   = ((j >> 3) & 15) * TQ;
    const int wq0  = q0 + wq * 32;  // this wave's query base (32 rows)

    const unsigned short* Qp = Q + (size_t)bh * S_ * D_;
    const unsigned short* Kp = K + (size_t)bh * S_ * D_;
    const unsigned short* Vp = V + (size_t)bh * S_ * D_;   // [s/32][64][s%32]

    // Q B-operand frags (n = q = l15), pre-scaled by log2(e)/8: [mt][ks]
    bf16x8 qf[2][2];
    #pragma unroll
    for (int mt = 0; mt < 2; ++mt)
        #pragma unroll
        for (int ks = 0; ks < 2; ++ks)
            qf[mt][ks] = *(const bf16x8*)(Qp + (size_t)(wq0 + mt*16 + l15) * D_
                                          + ks*32 + quad*8);

    bf16x8 ones;
    #pragma unroll
    for (int i = 0; i < 8; ++i) ones[i] = (short)0x3F80;   // bf16 1.0

    f32x4 Oacc[2][4];
    #pragma unroll
    for (int mt = 0; mt < 2; ++mt)
        #pragma unroll
        for (int nt = 0; nt < 4; ++nt)
            #pragma unroll
            for (int r = 0; r < 4; ++r) Oacc[mt][nt][r] = 0.f;
    f32x4 Dacc[2];
    #pragma unroll
    for (int mt = 0; mt < 2; ++mt)
        #pragma unroll
        for (int r = 0; r < 4; ++r) Dacc[mt][r] = 0.f;

    // K staging: 512 threads, 1 gload16 per half; rows 0..63
    const int srow = t >> 3;                          // 0..63
    const int gch  = ((t & 7) ^ (srow & 7)) * 8;      // swizzle-inverse (shorts)
    const unsigned short* kg0 = Kp + (size_t)srow * D_ + gch;          // keys 0..63
    const unsigned short* kg1 = Kp + (size_t)(srow + 64) * D_ + gch;   // keys 64..127

    // V frag base: elem = (k0/32 + wk*2 + ks)*2048 + (nt*16+l15)*32 + quad*8
    // lanes tile a contiguous 1KB block per (ks,nt) -> fully coalesced.
    const unsigned short* vbase = Vp + wk * 2 * 2048 + l15 * 32 + quad * 8;

    // prologue: stage K tile 0 into buffer 0
    {
        unsigned short* nb = KV[0];
        gload16(kg0, nb + t*8);
        gload16(kg1, nb + 4096 + t*8);
        kg0 += TK * D_; kg1 += TK * D_;
    }
    __syncthreads();                 // vmcnt drained -> buf0 ready

    int cur = 0;
    for (int k0 = 0; k0 < S_; k0 += TK) {
        // issue next-tile K staging into the other buffer (overlaps compute)
        if (k0 + TK < S_) {
            unsigned short* nb = KV[cur ^ 1];
            gload16(kg0, nb + t*8);
            gload16(kg1, nb + 4096 + t*8);
            kg0 += TK * D_; kg1 += TK * D_;
        }
        const unsigned short* KsW = &KV[cur][wk * 4096];
        const unsigned short* vtile = vbase + (size_t)k0 * 64;

        // ---- S^T = K Q^T : 64 keys (4 kt of 16) x 32 q (2 mt) per wave ----
        f32x4 sacc[2][4];
        #pragma unroll
        for (int mt = 0; mt < 2; ++mt)
            #pragma unroll
            for (int kt = 0; kt < 4; ++kt)
                #pragma unroll
                for (int r = 0; r < 4; ++r) sacc[mt][kt][r] = 0.f;
        __builtin_amdgcn_s_setprio(1);
        #pragma unroll
        for (int kt = 0; kt < 4; ++kt) {
            bf16x8 kf0 = *(const bf16x8*)&KsW[SWZ(kt*16 + l15, quad)];
            bf16x8 kf1 = *(const bf16x8*)&KsW[SWZ(kt*16 + l15, 4 + quad)];
            #pragma unroll
            for (int mt = 0; mt < 2; ++mt) {
                sacc[mt][kt] = __builtin_amdgcn_mfma_f32_16x16x32_bf16(
                    kf0, qf[mt][0], sacc[mt][kt], 0, 0, 0);
                sacc[mt][kt] = __builtin_amdgcn_mfma_f32_16x16x32_bf16(
                    kf1, qf[mt][1], sacc[mt][kt], 0, 0, 0);
            }
        }
        __builtin_amdgcn_s_setprio(0);

        // ---- issue V (ks=0) loads early: exp/pack phase covers L2 latency --
        bf16x8 vf0[4];
        #pragma unroll
        for (int nt = 0; nt < 4; ++nt)
            vf0[nt] = *(const bf16x8*)(vtile + nt * 512);

        // ---- exp2 + (rare) inverted-window mask; pack to bf16 in-register --
        unsigned int dw[2][4][2];
        #pragma unroll
        for (int mt = 0; mt < 2; ++mt) {
            const int qt0 = wq0 + mt*16;
            #pragma unroll
            for (int kt = 0; kt < 4; ++kt) {
                const int kt0 = k0 + wk*64 + kt*16;
                const bool band = (unsigned)(qt0 - kt0 + 18) <= 36u;  // wave-uniform
                float p[4];
                if (band) {
                    #pragma unroll
                    for (int r = 0; r < 4; ++r) {
                        int dlt = (qt0 + l15) - (kt0 + quad*4 + r);
                        if (dlt < 0) dlt = -dlt;
                        p[r] = (dlt <= WIN_) ? 0.f
                             : __builtin_amdgcn_exp2f(sacc[mt][kt][r]);
                    }
                } else {
                    #pragma unroll
                    for (int r = 0; r < 4; ++r)
                        p[r] = __builtin_amdgcn_exp2f(sacc[mt][kt][r]);
                }
                dw[mt][kt][0] = cvt_pk_bf16(p[0], p[1]);   // keys quad*4+{0,1}
                dw[mt][kt][1] = cvt_pk_bf16(p[2], p[3]);   // keys quad*4+{2,3}
            }
        }

        // ---- lane-swap P into PV A-frags: lane needs keys ks*32+quad*8..+7 -
        bf16x8 pa[2][2];
        #pragma unroll
        for (int mt = 0; mt < 2; ++mt) {
            #pragma unroll
            for (int ks = 0; ks < 2; ++ks) {
                uintx2 s0 = __builtin_amdgcn_permlane32_swap(
                    dw[mt][2*ks][0], dw[mt][2*ks + 1][0], false, false);
                uintx2 a02 = __builtin_amdgcn_permlane16_swap(
                    s0.x, s0.y, false, false);
                uintx2 s1 = __builtin_amdgcn_permlane32_swap(
                    dw[mt][2*ks][1], dw[mt][2*ks + 1][1], false, false);
                uintx2 a13 = __builtin_amdgcn_permlane16_swap(
                    s1.x, s1.y, false, false);
                union { unsigned int d[4]; bf16x8 v; } u;
                u.d[0] = a02.x;   // keys quad*8+{0,1}
                u.d[1] = a13.x;   // keys quad*8+{2,3}
                u.d[2] = a02.y;   // keys quad*8+{4,5}
                u.d[3] = a13.y;   // keys quad*8+{6,7}
                pa[mt][ks] = u.v;
            }
        }

        // ---- O += P V ; D += P 1 over this wave's key half ----
        // ks=1 V loads issued here; consumed after the ks=0 MFMA block.
        bf16x8 vf1[4];
        #pragma unroll
        for (int nt = 0; nt < 4; ++nt)
            vf1[nt] = *(const bf16x8*)(vtile + 2048 + nt * 512);

        __builtin_amdgcn_s_setprio(1);
        #pragma unroll
        for (int mt = 0; mt < 2; ++mt) {
            Dacc[mt] = __builtin_amdgcn_mfma_f32_16x16x32_bf16(
                pa[mt][0], ones, Dacc[mt], 0, 0, 0);
            Dacc[mt] = __builtin_amdgcn_mfma_f32_16x16x32_bf16(
                pa[mt][1], ones, Dacc[mt], 0, 0, 0);
        }
        #pragma unroll
        for (int nt = 0; nt < 4; ++nt)
            #pragma unroll
            for (int mt = 0; mt < 2; ++mt)
                Oacc[mt][nt] = __builtin_amdgcn_mfma_f32_16x16x32_bf16(
                    pa[mt][0], vf0[nt], Oacc[mt][nt], 0, 0, 0);
        #pragma unroll
        for (int nt = 0; nt < 4; ++nt)
            #pragma unroll
            for (int mt = 0; mt < 2; ++mt)
                Oacc[mt][nt] = __builtin_amdgcn_mfma_f32_16x16x32_bf16(
                    pa[mt][1], vf1[nt], Oacc[mt][nt], 0, 0, 0);
        __builtin_amdgcn_s_setprio(0);

        __syncthreads();   // all waves done with KV[cur]; next buffer's loads
                           // drained by the barrier's vmcnt(0)
        cur ^= 1;
    }

    // ---- merge key halves through LDS (Oex spans both K buffers; 32 KB) ----
    float* Oex = (float*)KV;             // 8192 floats = 32 KB
    if (wk == 1) {
        #pragma unroll
        for (int mt = 0; mt < 2; ++mt) {
            #pragma unroll
            for (int r = 0; r < 4; ++r) {
                const int qrow = wq*32 + mt*16 + quad*4 + r;
                Dex[qrow] = Dacc[mt][r];             // 16 lanes same value: benign
                #pragma unroll
                for (int nt = 0; nt < 4; ++nt)
                    Oex[qrow * 64 + nt*16 + l15] = Oacc[mt][nt][r];
            }
        }
    }
    __syncthreads();                     // Oex/Dex visible
    if (wk == 0) {
        const int b  = bh >> 4;
        const int hh = bh & 15;
        #pragma unroll
        for (int mt = 0; mt < 2; ++mt) {
            #pragma unroll
            for (int r = 0; r < 4; ++r) {
                const int qrow = wq*32 + mt*16 + quad*4 + r;
                const float iv = 1.f / (Dacc[mt][r] + Dex[qrow]);
                const int qg = q0 + qrow;
                float* op = out + (((size_t)b * S_ + qg) * H_ + hh) * D_;
                #pragma unroll
                for (int nt = 0; nt < 4; ++nt)
                    op[nt*16 + l15] =
                        (Oacc[mt][nt][r] + Oex[qrow * 64 + nt*16 + l15]) * iv;
            }
        }
    }
}

extern "C" void kernel_launch(void* const* d_in, const int* in_sizes, int n_in,
                              void* d_out, int out_size, void* d_ws, size_t ws_size,
                              hipStream_t stream) {
    const float* x  = (const float*)d_in[0];
    const float* Wq = (const float*)d_in[1];
    const float* bq = (const float*)d_in[2];
    const float* Wk = (const float*)d_in[3];
    const float* bk = (const float*)d_in[4];
    const float* Wv = (const float*)d_in[5];
    const float* bv = (const float*)d_in[6];
    float* out = (float*)d_out;

    const size_t per = (size_t)B_ * H_ * S_ * D_;   // 4,194,304 elements
    const size_t wsz = (size_t)E_ * E_;             // 1,048,576
    unsigned short* qb  = (unsigned short*)d_ws;
    unsigned short* kb  = qb + per;
    unsigned short* vb  = kb + per;
    unsigned short* xbf = vb + per;
    unsigned short* wqb = xbf + per;
    unsigned short* wkb = wqb + wsz;
    unsigned short* wvb = wkb + wsz;

    dim3 cgrid((B_ * S_ * E_ + 2047) / 2048, 4);
    cast_kernel<<<cgrid, 256, 0, stream>>>(x, Wq, Wk, Wv, xbf, wqb, wkb, wvb);

    dim3 ggrid(B_ * S_ / 128, E_ / 128, 3);
    gemm_kernel<<<ggrid, 256, 0, stream>>>(xbf, wqb, wkb, wvb, bq, bk, bv, qb, kb, vb);

    attn_kernel<<<dim3(512), 512, 0, stream>>>(qb, kb, vb, out);
}

// Round 8
// 155.685 us; speedup vs baseline: 1.0559x; 1.0559x over previous
//
#include <hip/hip_runtime.h>
#include <hip/hip_bf16.h>
#include <cstddef>
#include <cstdint>

#define B_ 2
#define S_ 2048
#define E_ 1024
#define H_ 16
#define D_ 64
#define WIN_ 3

using bf16x8 = __attribute__((ext_vector_type(8))) short;  // 8 bf16 = 4 VGPRs
using f32x4  = __attribute__((ext_vector_type(4))) float;  // MFMA C/D
using uintx2 = __attribute__((ext_vector_type(2))) unsigned int;

static __device__ __forceinline__ unsigned short f2bf(float f) {
    union { float f; unsigned int u; } c; c.f = f;
    unsigned int r = c.u + 0x7FFF + ((c.u >> 16) & 1);   // round-to-nearest-even
    return (unsigned short)(r >> 16);
}

static __device__ __forceinline__ void gload16(const void* g, void* l) {
    __builtin_amdgcn_global_load_lds(
        (const __attribute__((address_space(1))) void*)g,
        (__attribute__((address_space(3))) void*)l, 16, 0, 0);
}

static __device__ __forceinline__ unsigned int cvt_pk_bf16(float a, float b) {
    unsigned int d;
    asm("v_cvt_pk_bf16_f32 %0, %1, %2" : "=v"(d) : "v"(a), "v"(b));
    return d;  // lo half = bf16(a), hi half = bf16(b)
}

// XOR-swizzled LDS index (shorts) for [row][chunk-of-8-shorts] tiles with
// 64-short rows: slot = chunk ^ (row & 7). Breaks the 128B-row bank aliasing
// while staying global_load_lds-compatible (lane*16B contiguous).
#define SWZ(row, c) ((((row) * 8) + ((c) ^ ((row) & 7))) * 8)

// ---------------------------------------------------------------------------
// fp32 -> bf16 cast: y=0: x (4M elems), y=1..3: Wq/Wk/Wv (1M each)
// ---------------------------------------------------------------------------
__global__ __launch_bounds__(256) void cast_kernel(
    const float* __restrict__ X,  const float* __restrict__ Wq,
    const float* __restrict__ Wk, const float* __restrict__ Wv,
    unsigned short* __restrict__ xb,  unsigned short* __restrict__ wqb,
    unsigned short* __restrict__ wkb, unsigned short* __restrict__ wvb)
{
    const float* src; unsigned short* dst; int n;
    switch (blockIdx.y) {
        case 0:  src = X;  dst = xb;  n = B_ * S_ * E_; break;
        case 1:  src = Wq; dst = wqb; n = E_ * E_;      break;
        case 2:  src = Wk; dst = wkb; n = E_ * E_;      break;
        default: src = Wv; dst = wvb; n = E_ * E_;      break;
    }
    int i = (blockIdx.x * 256 + threadIdx.x) * 8;
    if (i >= n) return;
    float4 a = *(const float4*)(src + i);
    float4 b = *(const float4*)(src + i + 4);
    ushort4 lo, hi;
    lo.x = f2bf(a.x); lo.y = f2bf(a.y); lo.z = f2bf(a.z); lo.w = f2bf(a.w);
    hi.x = f2bf(b.x); hi.y = f2bf(b.y); hi.z = f2bf(b.z); hi.w = f2bf(b.w);
    *(ushort4*)(dst + i)     = lo;
    *(ushort4*)(dst + i + 4) = hi;
}

// ---------------------------------------------------------------------------
// bf16 MFMA projection GEMM (m97 structure + swizzled LDS):
// C[i,j] = sum_k A[i,k]*B[j,k]; 128x128 tile, BK=64, 4 waves, 4x4 frags.
// z=0: A=x, B=Wq -> q bf16 [B,H,S,D] scaled log2(e)/8 (exp2 softmax path)
// z=1: A=x, B=Wk -> k bf16 [B,H,S,D]
// z=2: A=Wv, B=x (swapped) -> v bf16 in FRAGMENT-NATIVE layout
//      [bh][s/32][d=64][s%32]: the attn V B-frag read (lane(l15,quad) ->
//      d*32 + quad*8 shorts) is a fully contiguous 1KB/instruction load.
//
// XCD tiling (R14, kept): bijective 8x12 rectangles; A+B panels L2-resident.
// ---------------------------------------------------------------------------
__global__ __launch_bounds__(256, 4) void gemm_kernel(
    const unsigned short* __restrict__ xb,
    const unsigned short* __restrict__ wqb, const unsigned short* __restrict__ wkb,
    const unsigned short* __restrict__ wvb,
    const float* __restrict__ bq, const float* __restrict__ bk,
    const float* __restrict__ bv,
    unsigned short* __restrict__ qb, unsigned short* __restrict__ kb,
    unsigned short* __restrict__ vb)
{
    constexpr int BM = 128, BK = 64;
    __shared__ unsigned short As[BM * BK];
    __shared__ unsigned short Bs[BM * BK];

    const int t    = threadIdx.x;
    const int lane = t & 63;
    const int w    = t >> 6;
    const int l15  = lane & 15;
    const int quad = lane >> 4;
    const int wm   = w & 1;
    const int wn   = w >> 1;

    // --- XCD-tiled work assignment (bijective over 768 blocks) ---
    const int l   = blockIdx.x + (blockIdx.y << 5) + (blockIdx.z << 8);
    const int ix  = l & 7;          // XCD id (hw round-robin)
    const int p   = l >> 3;         // position within XCD's 96-block share
    const int x2  = (ix & 3) * 8 + (p & 7);         // m-block 0..31
    const int yz  = (ix >> 2) * 12 + (p >> 3);      // (n,z) 0..23
    const int m0  = x2 * BM;
    const int n0  = (yz & 7) * BM;
    const int z   = yz >> 3;

    const unsigned short *Ab, *Bb; const float* bias; unsigned short* outp;
    int i0, j0; float sc = 1.0f;
    if (z == 0)      { Ab = xb;  Bb = wqb; bias = bq; outp = qb; i0 = m0; j0 = n0;
                       sc = 0.125f * 1.44269504088896f; }
    else if (z == 1) { Ab = xb;  Bb = wkb; bias = bk; outp = kb; i0 = m0; j0 = n0; }
    else             { Ab = wvb; Bb = xb;  bias = bv; outp = vb; i0 = n0; j0 = m0; }

    const int lrow = lane >> 3;
    const int gch  = ((lane & 7) ^ (lrow & 7)) * 8;
    const int lsl  = (lane & 7) * 8;

    f32x4 acc[4][4];
    #pragma unroll
    for (int mt = 0; mt < 4; ++mt)
        #pragma unroll
        for (int nt = 0; nt < 4; ++nt)
            #pragma unroll
            for (int r = 0; r < 4; ++r) acc[mt][nt][r] = 0.f;

    for (int k0 = 0; k0 < E_; k0 += BK) {
        __syncthreads();
        #pragma unroll
        for (int is = 0; is < 4; ++is) {
            int r = (w * 4 + is) * 8 + lrow;
            gload16(Ab + (size_t)(i0 + r) * E_ + k0 + gch, &As[r * BK + lsl]);
            gload16(Bb + (size_t)(j0 + r) * E_ + k0 + gch, &Bs[r * BK + lsl]);
        }
        __syncthreads();

        #pragma unroll
        for (int ks = 0; ks < 2; ++ks) {
            bf16x8 af[4], bfr[4];
            #pragma unroll
            for (int mt = 0; mt < 4; ++mt)
                af[mt] = *(const bf16x8*)&As[SWZ(wm*64 + mt*16 + l15, ks*4 + quad)];
            #pragma unroll
            for (int nt = 0; nt < 4; ++nt)
                bfr[nt] = *(const bf16x8*)&Bs[SWZ(wn*64 + nt*16 + l15, ks*4 + quad)];
            #pragma unroll
            for (int mt = 0; mt < 4; ++mt)
                #pragma unroll
                for (int nt = 0; nt < 4; ++nt)
                    acc[mt][nt] = __builtin_amdgcn_mfma_f32_16x16x32_bf16(
                        af[mt], bfr[nt], acc[mt][nt], 0, 0, 0);
        }
    }

    if (z < 2) {
        float bj[4];
        #pragma unroll
        for (int nt = 0; nt < 4; ++nt) bj[nt] = bias[j0 + wn*64 + nt*16 + l15];
        #pragma unroll
        for (int mt = 0; mt < 4; ++mt) {
            #pragma unroll
            for (int r = 0; r < 4; ++r) {
                int i = i0 + wm*64 + mt*16 + quad*4 + r;
                int b = i >> 11, s = i & (S_ - 1);
                #pragma unroll
                for (int nt = 0; nt < 4; ++nt) {
                    int jj = j0 + wn*64 + nt*16 + l15;
                    int hh = jj >> 6, d = jj & 63;
                    outp[(((size_t)(b * H_ + hh) * S_) + s) * D_ + d] =
                        f2bf((acc[mt][nt][r] + bj[nt]) * sc);
                }
            }
        }
    } else {
        // V store in fragment-native layout [bh][s/32][64][s%32]:
        // elem = ((bh*64 + (s>>5))*64 + d)*32 + (s&31)
        #pragma unroll
        for (int mt = 0; mt < 4; ++mt) {
            #pragma unroll
            for (int r = 0; r < 4; ++r) {
                int i = i0 + wm*64 + mt*16 + quad*4 + r;
                int hh = i >> 6, d = i & 63;
                float bi = bias[i];
                #pragma unroll
                for (int nt = 0; nt < 4; ++nt) {
                    int jj = j0 + wn*64 + nt*16 + l15;
                    int b = jj >> 11, s = jj & (S_ - 1);
                    outp[(((size_t)((b * H_ + hh) * (S_/32) + (s >> 5)) * D_ + d)
                          * 32) + (s & 31)] =
                        f2bf(acc[mt][nt][r] + bi);
                }
            }
        }
    }
}

// ---------------------------------------------------------------------------
// MFMA attention, R16: V L2-direct (fragment-native layout) with CORRECT
// vmcnt ordering + half-tile pipelining.
//
// R15 post-mortem: gload16 and V vector loads share the in-order vmcnt
// counter. R15 issued [stage, vf0, ..., vf1]; PV's wait for vf retired the
// OLDER staging loads too -> K prefetch force-drained mid-iteration
// (single-buffering in disguise) AND vf1 had ~100cy cover. Fixes:
//  * vf(ks=0) issued at iteration TOP, BEFORE the staging gload16s ->
//    PV-ks0 waits vmcnt(<=2), staging stays in flight.
//  * iteration split into two 32-key halves (QK kt{0,1} -> exp/pack ->
//    permlane -> PV-ks0, then same for kt{2,3}); vf(ks=1) issued at half-B
//    start (cover = half-B exp/pack; its wait drains staging only after
//    ~1000cy, just before the barrier that drains it anyway).
//  * halved sacc/dw liveness keeps peak VGPR ~115 < 128 (2 blocks/CU).
// vs R9: LDS-read pipe per block-iter 1536 -> 768 cy, V off LDS entirely,
// staging overlap preserved. Spill guard: WRITE_SIZE (~16-20MB ok).
// q pre-scaled by log2(e)/8 in gemm -> raw v_exp2_f32 here.
// XCD swizzle: bh = (j&7)*4 + (j>>7) keeps each XCD on 4 bh (L2-resident).
// ---------------------------------------------------------------------------
__global__ __launch_bounds__(512, 4) void attn_kernel(
    const unsigned short* __restrict__ Q, const unsigned short* __restrict__ K,
    const unsigned short* __restrict__ V, float* __restrict__ out)
{
    constexpr int TQ = 128, TK = 128;
    // per buffer (8192 shorts = 16KB): Ks0 @0 (keys 0..63), Ks1 @4096 (64..127)
    __shared__ unsigned short KV[2][8192];
    __shared__ float          Dex[TQ];

    const int t    = threadIdx.x;
    const int lane = t & 63;
    const int w    = t >> 6;        // wave 0..7
    const int wq   = w & 3;         // q-group (32 rows)
    const int wk   = w >> 2;        // key half
    const int l15  = lane & 15;
    const int quad = lane >> 4;

    const int j    = blockIdx.x;
    const int bh   = (j & 7) * 4 + (j >> 7);
    const int q0   = ((j >> 3) & 15) * TQ;
    const int wq0  = q0 + wq * 32;  // this wave's query base (32 rows)

    const unsigned short* Qp = Q + (size_t)bh * S_ * D_;
    const unsigned short* Kp = K + (size_t)bh * S_ * D_;
    const unsigned short* Vp = V + (size_t)bh * S_ * D_;   // [s/32][64][s%32]

    // Q B-operand frags (n = q = l15), pre-scaled by log2(e)/8: [mt][ks]
    bf16x8 qf[2][2];
    #pragma unroll
    for (int mt = 0; mt < 2; ++mt)
        #pragma unroll
        for (int ks = 0; ks < 2; ++ks)
            qf[mt][ks] = *(const bf16x8*)(Qp + (size_t)(wq0 + mt*16 + l15) * D_
                                          + ks*32 + quad*8);

    bf16x8 ones;
    #pragma unroll
    for (int i = 0; i < 8; ++i) ones[i] = (short)0x3F80;   // bf16 1.0

    f32x4 Oacc[2][4];
    #pragma unroll
    for (int mt = 0; mt < 2; ++mt)
        #pragma unroll
        for (int nt = 0; nt < 4; ++nt)
            #pragma unroll
            for (int r = 0; r < 4; ++r) Oacc[mt][nt][r] = 0.f;
    f32x4 Dacc[2];
    #pragma unroll
    for (int mt = 0; mt < 2; ++mt)
        #pragma unroll
        for (int r = 0; r < 4; ++r) Dacc[mt][r] = 0.f;

    // K staging: 512 threads, 1 gload16 per half; rows 0..63
    const int srow = t >> 3;                          // 0..63
    const int gch  = ((t & 7) ^ (srow & 7)) * 8;      // swizzle-inverse (shorts)
    const unsigned short* kg0 = Kp + (size_t)srow * D_ + gch;          // keys 0..63
    const unsigned short* kg1 = Kp + (size_t)(srow + 64) * D_ + gch;   // keys 64..127

    // V frag base: elem = (k0/32 + wk*2 + ks)*2048 + (nt*16+l15)*32 + quad*8
    const unsigned short* vbase = Vp + wk * 2 * 2048 + l15 * 32 + quad * 8;

    // prologue: stage K tile 0 into buffer 0
    {
        unsigned short* nb = KV[0];
        gload16(kg0, nb + t*8);
        gload16(kg1, nb + 4096 + t*8);
        kg0 += TK * D_; kg1 += TK * D_;
    }
    __syncthreads();                 // vmcnt drained -> buf0 ready

    int cur = 0;
    for (int k0 = 0; k0 < S_; k0 += TK) {
        const unsigned short* vtile = vbase + (size_t)k0 * 64;

        // ---- V ks=0 frags FIRST (oldest vmcnt slots): PV-ks0's wait
        //      retires these without touching the staging loads below ----
        bf16x8 vfc[4];
        #pragma unroll
        for (int nt = 0; nt < 4; ++nt)
            vfc[nt] = *(const bf16x8*)(vtile + nt * 512);

        // ---- next-tile K staging (younger than vfc -> survives PV-ks0) ----
        if (k0 + TK < S_) {
            unsigned short* nb = KV[cur ^ 1];
            gload16(kg0, nb + t*8);
            gload16(kg1, nb + 4096 + t*8);
            kg0 += TK * D_; kg1 += TK * D_;
        }
        const unsigned short* KsW = &KV[cur][wk * 4096];

        // ---- two 32-key halves, each fully pipelined ----
        #pragma unroll
        for (int ks2 = 0; ks2 < 2; ++ks2) {
            if (ks2 == 1) {
                // V ks=1 frags; cover = half-B exp/pack (~400cy). Their wait
                // drains staging, but staging has had ~1000cy by then and the
                // barrier would drain it anyway.
                #pragma unroll
                for (int nt = 0; nt < 4; ++nt)
                    vfc[nt] = *(const bf16x8*)(vtile + 2048 + nt * 512);
            }

            // ---- S^T = K Q^T : 32 keys (2 kt) x 32 q (2 mt) per wave ----
            f32x4 sacc[2][2];
            #pragma unroll
            for (int mt = 0; mt < 2; ++mt)
                #pragma unroll
                for (int kt2 = 0; kt2 < 2; ++kt2)
                    #pragma unroll
                    for (int r = 0; r < 4; ++r) sacc[mt][kt2][r] = 0.f;
            __builtin_amdgcn_s_setprio(1);
            #pragma unroll
            for (int kt2 = 0; kt2 < 2; ++kt2) {
                const int kt = ks2*2 + kt2;
                bf16x8 kf0 = *(const bf16x8*)&KsW[SWZ(kt*16 + l15, quad)];
                bf16x8 kf1 = *(const bf16x8*)&KsW[SWZ(kt*16 + l15, 4 + quad)];
                #pragma unroll
                for (int mt = 0; mt < 2; ++mt) {
                    sacc[mt][kt2] = __builtin_amdgcn_mfma_f32_16x16x32_bf16(
                        kf0, qf[mt][0], sacc[mt][kt2], 0, 0, 0);
                    sacc[mt][kt2] = __builtin_amdgcn_mfma_f32_16x16x32_bf16(
                        kf1, qf[mt][1], sacc[mt][kt2], 0, 0, 0);
                }
            }
            __builtin_amdgcn_s_setprio(0);

            // ---- exp2 + (rare) inverted-window mask; pack to bf16 ----
            unsigned int dw[2][2][2];
            #pragma unroll
            for (int mt = 0; mt < 2; ++mt) {
                const int qt0 = wq0 + mt*16;
                #pragma unroll
                for (int kt2 = 0; kt2 < 2; ++kt2) {
                    const int kt0 = k0 + wk*64 + (ks2*2 + kt2)*16;
                    const bool band = (unsigned)(qt0 - kt0 + 18) <= 36u;
                    float p[4];
                    if (band) {
                        #pragma unroll
                        for (int r = 0; r < 4; ++r) {
                            int dlt = (qt0 + l15) - (kt0 + quad*4 + r);
                            if (dlt < 0) dlt = -dlt;
                            p[r] = (dlt <= WIN_) ? 0.f
                                 : __builtin_amdgcn_exp2f(sacc[mt][kt2][r]);
                        }
                    } else {
                        #pragma unroll
                        for (int r = 0; r < 4; ++r)
                            p[r] = __builtin_amdgcn_exp2f(sacc[mt][kt2][r]);
                    }
                    dw[mt][kt2][0] = cvt_pk_bf16(p[0], p[1]);  // keys quad*4+{0,1}
                    dw[mt][kt2][1] = cvt_pk_bf16(p[2], p[3]);  // keys quad*4+{2,3}
                }
            }

            // ---- lane-swap P into PV A-frag: lane needs keys quad*8..+7 ----
            bf16x8 pa[2];
            #pragma unroll
            for (int mt = 0; mt < 2; ++mt) {
                uintx2 s0 = __builtin_amdgcn_permlane32_swap(
                    dw[mt][0][0], dw[mt][1][0], false, false);
                uintx2 a02 = __builtin_amdgcn_permlane16_swap(
                    s0.x, s0.y, false, false);
                uintx2 s1 = __builtin_amdgcn_permlane32_swap(
                    dw[mt][0][1], dw[mt][1][1], false, false);
                uintx2 a13 = __builtin_amdgcn_permlane16_swap(
                    s1.x, s1.y, false, false);
                union { unsigned int d[4]; bf16x8 v; } u;
                u.d[0] = a02.x;   // keys quad*8+{0,1}
                u.d[1] = a13.x;   // keys quad*8+{2,3}
                u.d[2] = a02.y;   // keys quad*8+{4,5}
                u.d[3] = a13.y;   // keys quad*8+{6,7}
                pa[mt] = u.v;
            }

            // ---- O += P V ; D += P 1 over this 32-key half ----
            __builtin_amdgcn_s_setprio(1);
            #pragma unroll
            for (int mt = 0; mt < 2; ++mt)
                Dacc[mt] = __builtin_amdgcn_mfma_f32_16x16x32_bf16(
                    pa[mt], ones, Dacc[mt], 0, 0, 0);
            #pragma unroll
            for (int nt = 0; nt < 4; ++nt)
                #pragma unroll
                for (int mt = 0; mt < 2; ++mt)
                    Oacc[mt][nt] = __builtin_amdgcn_mfma_f32_16x16x32_bf16(
                        pa[mt], vfc[nt], Oacc[mt][nt], 0, 0, 0);
            __builtin_amdgcn_s_setprio(0);
        }

        __syncthreads();   // all waves done with KV[cur]; next buffer's loads
                           // drained by the barrier's vmcnt(0)
        cur ^= 1;
    }

    // ---- merge key halves through LDS (Oex spans both K buffers; 32 KB) ----
    float* Oex = (float*)KV;             // 8192 floats = 32 KB
    if (wk == 1) {
        #pragma unroll
        for (int mt = 0; mt < 2; ++mt) {
            #pragma unroll
            for (int r = 0; r < 4; ++r) {
                const int qrow = wq*32 + mt*16 + quad*4 + r;
                Dex[qrow] = Dacc[mt][r];             // 16 lanes same value: benign
                #pragma unroll
                for (int nt = 0; nt < 4; ++nt)
                    Oex[qrow * 64 + nt*16 + l15] = Oacc[mt][nt][r];
            }
        }
    }
    __syncthreads();                     // Oex/Dex visible
    if (wk == 0) {
        const int b  = bh >> 4;
        const int hh = bh & 15;
        #pragma unroll
        for (int mt = 0; mt < 2; ++mt) {
            #pragma unroll
            for (int r = 0; r < 4; ++r) {
                const int qrow = wq*32 + mt*16 + quad*4 + r;
                const float iv = 1.f / (Dacc[mt][r] + Dex[qrow]);
                const int qg = q0 + qrow;
                float* op = out + (((size_t)b * S_ + qg) * H_ + hh) * D_;
                #pragma unroll
                for (int nt = 0; nt < 4; ++nt)
                    op[nt*16 + l15] =
                        (Oacc[mt][nt][r] + Oex[qrow * 64 + nt*16 + l15]) * iv;
            }
        }
    }
}

extern "C" void kernel_launch(void* const* d_in, const int* in_sizes, int n_in,
                              void* d_out, int out_size, void* d_ws, size_t ws_size,
                              hipStream_t stream) {
    const float* x  = (const float*)d_in[0];
    const float* Wq = (const float*)d_in[1];
    const float* bq = (const float*)d_in[2];
    const float* Wk = (const float*)d_in[3];
    const float* bk = (const float*)d_in[4];
    const float* Wv = (const float*)d_in[5];
    const float* bv = (const float*)d_in[6];
    float* out = (float*)d_out;

    const size_t per = (size_t)B_ * H_ * S_ * D_;   // 4,194,304 elements
    const size_t wsz = (size_t)E_ * E_;             // 1,048,576
    unsigned short* qb  = (unsigned short*)d_ws;
    unsigned short* kb  = qb + per;
    unsigned short* vb  = kb + per;
    unsigned short* xbf = vb + per;
    unsigned short* wqb = xbf + per;
    unsigned short* wkb = wqb + wsz;
    unsigned short* wvb = wkb + wsz;

    dim3 cgrid((B_ * S_ * E_ + 2047) / 2048, 4);
    cast_kernel<<<cgrid, 256, 0, stream>>>(x, Wq, Wk, Wv, xbf, wqb, wkb, wvb);

    dim3 ggrid(B_ * S_ / 128, E_ / 128, 3);
    gemm_kernel<<<ggrid, 256, 0, stream>>>(xbf, wqb, wkb, wvb, bq, bk, bv, qb, kb, vb);

    attn_kernel<<<dim3(512), 512, 0, stream>>>(qb, kb, vb, out);
}

// Round 10
// 154.991 us; speedup vs baseline: 1.0606x; 1.0045x over previous
//
#include <hip/hip_runtime.h>
#include <hip/hip_bf16.h>
#include <cstddef>
#include <cstdint>

#define B_ 2
#define S_ 2048
#define E_ 1024
#define H_ 16
#define D_ 64
#define WIN_ 3

using bf16x8 = __attribute__((ext_vector_type(8))) short;  // 8 bf16 = 4 VGPRs
using f32x4  = __attribute__((ext_vector_type(4))) float;  // MFMA C/D
using uintx2 = __attribute__((ext_vector_type(2))) unsigned int;

static __device__ __forceinline__ unsigned short f2bf(float f) {
    union { float f; unsigned int u; } c; c.f = f;
    unsigned int r = c.u + 0x7FFF + ((c.u >> 16) & 1);   // round-to-nearest-even
    return (unsigned short)(r >> 16);
}

static __device__ __forceinline__ void gload16(const void* g, void* l) {
    __builtin_amdgcn_global_load_lds(
        (const __attribute__((address_space(1))) void*)g,
        (__attribute__((address_space(3))) void*)l, 16, 0, 0);
}

static __device__ __forceinline__ unsigned int cvt_pk_bf16(float a, float b) {
    unsigned int d;
    asm("v_cvt_pk_bf16_f32 %0, %1, %2" : "=v"(d) : "v"(a), "v"(b));
    return d;  // lo half = bf16(a), hi half = bf16(b)
}

// XOR-swizzled LDS index (shorts) for [row][chunk-of-8-shorts] tiles with
// 64-short rows (attn K tiles): slot = chunk ^ (row & 7).
#define SWZ(row, c) ((((row) * 8) + ((c) ^ ((row) & 7))) * 8)
// Same idea for 32-short rows (gemm BK=32 tiles): 4 chunks/row, XOR with
// (row>>1)&3 -> max 2-way bank aliasing (free, m136), staging stays
// global_load_lds-compatible (linear dest, swizzle on the global source).
#define SWZG(row, c) ((((row) * 4) + ((c) ^ (((row) >> 1) & 3))) * 8)

// ---------------------------------------------------------------------------
// fp32 -> bf16 cast: y=0: x (4M elems), y=1..3: Wq/Wk/Wv (1M each)
// ---------------------------------------------------------------------------
__global__ __launch_bounds__(256) void cast_kernel(
    const float* __restrict__ X,  const float* __restrict__ Wq,
    const float* __restrict__ Wk, const float* __restrict__ Wv,
    unsigned short* __restrict__ xb,  unsigned short* __restrict__ wqb,
    unsigned short* __restrict__ wkb, unsigned short* __restrict__ wvb)
{
    const float* src; unsigned short* dst; int n;
    switch (blockIdx.y) {
        case 0:  src = X;  dst = xb;  n = B_ * S_ * E_; break;
        case 1:  src = Wq; dst = wqb; n = E_ * E_;      break;
        case 2:  src = Wk; dst = wkb; n = E_ * E_;      break;
        default: src = Wv; dst = wvb; n = E_ * E_;      break;
    }
    int i = (blockIdx.x * 256 + threadIdx.x) * 8;
    if (i >= n) return;
    float4 a = *(const float4*)(src + i);
    float4 b = *(const float4*)(src + i + 4);
    ushort4 lo, hi;
    lo.x = f2bf(a.x); lo.y = f2bf(a.y); lo.z = f2bf(a.z); lo.w = f2bf(a.w);
    hi.x = f2bf(b.x); hi.y = f2bf(b.y); hi.z = f2bf(b.z); hi.w = f2bf(b.w);
    *(ushort4*)(dst + i)     = lo;
    *(ushort4*)(dst + i + 4) = hi;
}

// ---------------------------------------------------------------------------
// bf16 MFMA projection GEMM, R17/R18: double-buffered staging (T3 minimum
// 2-phase), BK=32.
//
// Diagnosis (R16): total - attn - cast pins gemm at ~45us (~560 TF) while
// its pipe budget (LDS-read 15us + loads 10us + MFMA 3us) says ~30us -- the
// gap is the `barrier; stage; barrier; compute` pattern draining vmcnt with
// ZERO compute in flight every iteration. Fix = the rotation proven in the
// attn kernel since R9: stage(next tile) -> compute(current) -> one barrier.
// BK=32 keeps LDS at 2x(8+8)=32 KB (occupancy unchanged).
// Swizzle for 32-short rows: chunk ^ ((row>>1)&3) -> max 2-way conflicts;
// staging dest stays linear (t*16B), swizzle applied to the global source.
//
// C[i,j] = sum_k A[i,k]*B[j,k]; 128x128 tile, 4 waves, 4x4 frags.
// z=0: A=x, B=Wq -> q bf16 [B,H,S,D] scaled log2(e)/8 (exp2 softmax path)
// z=1: A=x, B=Wk -> k bf16 [B,H,S,D]
// z=2: A=Wv, B=x (swapped) -> v bf16 in FRAGMENT-NATIVE layout
//      [bh][s/32][d=64][s%32] (attn reads V L2-direct, 1KB/instr).
// XCD tiling (R14): bijective 8x12 rectangles; A+B panels L2-resident.
// ---------------------------------------------------------------------------
__global__ __launch_bounds__(256, 4) void gemm_kernel(
    const unsigned short* __restrict__ xb,
    const unsigned short* __restrict__ wqb, const unsigned short* __restrict__ wkb,
    const unsigned short* __restrict__ wvb,
    const float* __restrict__ bq, const float* __restrict__ bk,
    const float* __restrict__ bv,
    unsigned short* __restrict__ qb, unsigned short* __restrict__ kb,
    unsigned short* __restrict__ vb)
{
    constexpr int BM = 128, BK = 32;
    __shared__ unsigned short As[2][BM * BK];   // 8 KB per buffer
    __shared__ unsigned short Bs[2][BM * BK];

    const int t    = threadIdx.x;
    const int lane = t & 63;
    const int w    = t >> 6;
    const int l15  = lane & 15;
    const int quad = lane >> 4;
    const int wm   = w & 1;
    const int wn   = w >> 1;

    // --- XCD-tiled work assignment (bijective over 768 blocks) ---
    const int l   = blockIdx.x + (blockIdx.y << 5) + (blockIdx.z << 8);
    const int ix  = l & 7;          // XCD id (hw round-robin)
    const int p   = l >> 3;         // position within XCD's 96-block share
    const int x2  = (ix & 3) * 8 + (p & 7);         // m-block 0..31
    const int yz  = (ix >> 2) * 12 + (p >> 3);      // (n,z) 0..23
    const int m0  = x2 * BM;
    const int n0  = (yz & 7) * BM;
    const int z   = yz >> 3;

    const unsigned short *Ab, *Bb; const float* bias; unsigned short* outp;
    int i0, j0; float sc = 1.0f;
    if (z == 0)      { Ab = xb;  Bb = wqb; bias = bq; outp = qb; i0 = m0; j0 = n0;
                       sc = 0.125f * 1.44269504088896f; }
    else if (z == 1) { Ab = xb;  Bb = wkb; bias = bk; outp = kb; i0 = m0; j0 = n0; }
    else             { Ab = wvb; Bb = xb;  bias = bv; outp = vb; i0 = n0; j0 = m0; }

    // staging: thread t covers rows r0 = t>>2 and r1 = 64 + t>>2, chunk t&3.
    // dest is linear t*16B; swizzle-inverse applied to the global source.
    // (row 64+srow swizzle key: ((64+srow)>>1)&3 == (srow>>1)&3 since 32%4==0)
    const int srow = t >> 2;                               // 0..63
    const int gchg = (((t & 3) ^ ((srow >> 1) & 3))) * 8;  // shorts
    const unsigned short* ag0 = Ab + (size_t)(i0 + srow)      * E_ + gchg;
    const unsigned short* ag1 = Ab + (size_t)(i0 + 64 + srow) * E_ + gchg;
    const unsigned short* bg0 = Bb + (size_t)(j0 + srow)      * E_ + gchg;
    const unsigned short* bg1 = Bb + (size_t)(j0 + 64 + srow) * E_ + gchg;

    f32x4 acc[4][4];
    #pragma unroll
    for (int mt = 0; mt < 4; ++mt)
        #pragma unroll
        for (int nt = 0; nt < 4; ++nt)
            #pragma unroll
            for (int r = 0; r < 4; ++r) acc[mt][nt][r] = 0.f;

    // prologue: stage k-tile 0 into buffer 0
    gload16(ag0, &As[0][t * 8]);
    gload16(ag1, &As[0][2048 + t * 8]);
    gload16(bg0, &Bs[0][t * 8]);
    gload16(bg1, &Bs[0][2048 + t * 8]);
    ag0 += BK; ag1 += BK; bg0 += BK; bg1 += BK;
    __syncthreads();                 // vmcnt drained -> buf0 ready

    int cur = 0;
    for (int k0 = 0; k0 < E_; k0 += BK) {
        // stage next k-tile into the other buffer (overlaps compute below)
        if (k0 + BK < E_) {
            gload16(ag0, &As[cur ^ 1][t * 8]);
            gload16(ag1, &As[cur ^ 1][2048 + t * 8]);
            gload16(bg0, &Bs[cur ^ 1][t * 8]);
            gload16(bg1, &Bs[cur ^ 1][2048 + t * 8]);
            ag0 += BK; ag1 += BK; bg0 += BK; bg1 += BK;
        }

        bf16x8 af[4], bfr[4];
        #pragma unroll
        for (int mt = 0; mt < 4; ++mt)
            af[mt] = *(const bf16x8*)&As[cur][SWZG(wm*64 + mt*16 + l15, quad)];
        #pragma unroll
        for (int nt = 0; nt < 4; ++nt)
            bfr[nt] = *(const bf16x8*)&Bs[cur][SWZG(wn*64 + nt*16 + l15, quad)];
        #pragma unroll
        for (int mt = 0; mt < 4; ++mt)
            #pragma unroll
            for (int nt = 0; nt < 4; ++nt)
                acc[mt][nt] = __builtin_amdgcn_mfma_f32_16x16x32_bf16(
                    af[mt], bfr[nt], acc[mt][nt], 0, 0, 0);

        __syncthreads();   // all waves done reading [cur]; next buffer's
                           // loads drained by the barrier's vmcnt(0)
        cur ^= 1;
    }

    if (z < 2) {
        float bj[4];
        #pragma unroll
        for (int nt = 0; nt < 4; ++nt) bj[nt] = bias[j0 + wn*64 + nt*16 + l15];
        #pragma unroll
        for (int mt = 0; mt < 4; ++mt) {
            #pragma unroll
            for (int r = 0; r < 4; ++r) {
                int i = i0 + wm*64 + mt*16 + quad*4 + r;
                int b = i >> 11, s = i & (S_ - 1);
                #pragma unroll
                for (int nt = 0; nt < 4; ++nt) {
                    int jj = j0 + wn*64 + nt*16 + l15;
                    int hh = jj >> 6, d = jj & 63;
                    outp[(((size_t)(b * H_ + hh) * S_) + s) * D_ + d] =
                        f2bf((acc[mt][nt][r] + bj[nt]) * sc);
                }
            }
        }
    } else {
        // V store in fragment-native layout [bh][s/32][64][s%32]:
        // elem = ((bh*64 + (s>>5))*64 + d)*32 + (s&31)
        #pragma unroll
        for (int mt = 0; mt < 4; ++mt) {
            #pragma unroll
            for (int r = 0; r < 4; ++r) {
                int i = i0 + wm*64 + mt*16 + quad*4 + r;
                int hh = i >> 6, d = i & 63;
                float bi = bias[i];
                #pragma unroll
                for (int nt = 0; nt < 4; ++nt) {
                    int jj = j0 + wn*64 + nt*16 + l15;
                    int b = jj >> 11, s = jj & (S_ - 1);
                    outp[(((size_t)((b * H_ + hh) * (S_/32) + (s >> 5)) * D_ + d)
                          * 32) + (s & 31)] =
                        f2bf(acc[mt][nt][r] + bi);
                }
            }
        }
    }
}

// ---------------------------------------------------------------------------
// MFMA attention (unchanged from R16): R9 skeleton; K LDS-staged dbuf; V
// frags L2-direct via fragment-native layout; in-register P (cvt_pk +
// permlane); half-tile pipelining with correct vmcnt issue order. 48.6us
// plateau -- latency-bound at the grid/LDS/VGPR-capped 16 waves/CU.
// q pre-scaled by log2(e)/8 in gemm -> raw v_exp2_f32 here.
// XCD swizzle: bh = (j&7)*4 + (j>>7) keeps each XCD on 4 bh (L2-resident).
// ---------------------------------------------------------------------------
__global__ __launch_bounds__(512, 4) void attn_kernel(
    const unsigned short* __restrict__ Q, const unsigned short* __restrict__ K,
    const unsigned short* __restrict__ V, float* __restrict__ out)
{
    constexpr int TQ = 128, TK = 128;
    // per buffer (8192 shorts = 16KB): Ks0 @0 (keys 0..63), Ks1 @4096 (64..127)
    __shared__ unsigned short KV[2][8192];
    __shared__ float          Dex[TQ];

    const int t    = threadIdx.x;
    const int lane = t & 63;
    const int w    = t >> 6;        // wave 0..7
    const int wq   = w & 3;         // q-group (32 rows)
    const int wk   = w >> 2;        // key half
    const int l15  = lane & 15;
    const int quad = lane >> 4;

    const int j    = blockIdx.x;
    const int bh   = (j & 7) * 4 + (j >> 7);
    const int q0   = ((j >> 3) & 15) * TQ;
    const int wq0  = q0 + wq * 32;  // this wave's query base (32 rows)

    const unsigned short* Qp = Q + (size_t)bh * S_ * D_;
    const unsigned short* Kp = K + (size_t)bh * S_ * D_;
    const unsigned short* Vp = V + (size_t)bh * S_ * D_;   // [s/32][64][s%32]

    // Q B-operand frags (n = q = l15), pre-scaled by log2(e)/8: [mt][ks]
    bf16x8 qf[2][2];
    #pragma unroll
    for (int mt = 0; mt < 2; ++mt)
        #pragma unroll
        for (int ks = 0; ks < 2; ++ks)
            qf[mt][ks] = *(const bf16x8*)(Qp + (size_t)(wq0 + mt*16 + l15) * D_
                                          + ks*32 + quad*8);

    bf16x8 ones;
    #pragma unroll
    for (int i = 0; i < 8; ++i) ones[i] = (short)0x3F80;   // bf16 1.0

    f32x4 Oacc[2][4];
    #pragma unroll
    for (int mt = 0; mt < 2; ++mt)
        #pragma unroll
        for (int nt = 0; nt < 4; ++nt)
            #pragma unroll
            for (int r = 0; r < 4; ++r) Oacc[mt][nt][r] = 0.f;
    f32x4 Dacc[2];
    #pragma unroll
    for (int mt = 0; mt < 2; ++mt)
        #pragma unroll
        for (int r = 0; r < 4; ++r) Dacc[mt][r] = 0.f;

    // K staging: 512 threads, 1 gload16 per half; rows 0..63
    const int srow = t >> 3;                          // 0..63
    const int gch  = ((t & 7) ^ (srow & 7)) * 8;      // swizzle-inverse (shorts)
    const unsigned short* kg0 = Kp + (size_t)srow * D_ + gch;          // keys 0..63
    const unsigned short* kg1 = Kp + (size_t)(srow + 64) * D_ + gch;   // keys 64..127

    // V frag base: elem = (k0/32 + wk*2 + ks)*2048 + (nt*16+l15)*32 + quad*8
    const unsigned short* vbase = Vp + wk * 2 * 2048 + l15 * 32 + quad * 8;

    // prologue: stage K tile 0 into buffer 0
    {
        unsigned short* nb = KV[0];
        gload16(kg0, nb + t*8);
        gload16(kg1, nb + 4096 + t*8);
        kg0 += TK * D_; kg1 += TK * D_;
    }
    __syncthreads();                 // vmcnt drained -> buf0 ready

    int cur = 0;
    for (int k0 = 0; k0 < S_; k0 += TK) {
        const unsigned short* vtile = vbase + (size_t)k0 * 64;

        // ---- V ks=0 frags FIRST (oldest vmcnt slots): PV-ks0's wait
        //      retires these without touching the staging loads below ----
        bf16x8 vfc[4];
        #pragma unroll
        for (int nt = 0; nt < 4; ++nt)
            vfc[nt] = *(const bf16x8*)(vtile + nt * 512);

        // ---- next-tile K staging (younger than vfc -> survives PV-ks0) ----
        if (k0 + TK < S_) {
            unsigned short* nb = KV[cur ^ 1];
            gload16(kg0, nb + t*8);
            gload16(kg1, nb + 4096 + t*8);
            kg0 += TK * D_; kg1 += TK * D_;
        }
        const unsigned short* KsW = &KV[cur][wk * 4096];

        // ---- two 32-key halves, each fully pipelined ----
        #pragma unroll
        for (int ks2 = 0; ks2 < 2; ++ks2) {
            if (ks2 == 1) {
                #pragma unroll
                for (int nt = 0; nt < 4; ++nt)
                    vfc[nt] = *(const bf16x8*)(vtile + 2048 + nt * 512);
            }

            // ---- S^T = K Q^T : 32 keys (2 kt) x 32 q (2 mt) per wave ----
            f32x4 sacc[2][2];
            #pragma unroll
            for (int mt = 0; mt < 2; ++mt)
                #pragma unroll
                for (int kt2 = 0; kt2 < 2; ++kt2)
                    #pragma unroll
                    for (int r = 0; r < 4; ++r) sacc[mt][kt2][r] = 0.f;
            __builtin_amdgcn_s_setprio(1);
            #pragma unroll
            for (int kt2 = 0; kt2 < 2; ++kt2) {
                const int kt = ks2*2 + kt2;
                bf16x8 kf0 = *(const bf16x8*)&KsW[SWZ(kt*16 + l15, quad)];
                bf16x8 kf1 = *(const bf16x8*)&KsW[SWZ(kt*16 + l15, 4 + quad)];
                #pragma unroll
                for (int mt = 0; mt < 2; ++mt) {
                    sacc[mt][kt2] = __builtin_amdgcn_mfma_f32_16x16x32_bf16(
                        kf0, qf[mt][0], sacc[mt][kt2], 0, 0, 0);
                    sacc[mt][kt2] = __builtin_amdgcn_mfma_f32_16x16x32_bf16(
                        kf1, qf[mt][1], sacc[mt][kt2], 0, 0, 0);
                }
            }
            __builtin_amdgcn_s_setprio(0);

            // ---- exp2 + (rare) inverted-window mask; pack to bf16 ----
            unsigned int dw[2][2][2];
            #pragma unroll
            for (int mt = 0; mt < 2; ++mt) {
                const int qt0 = wq0 + mt*16;
                #pragma unroll
                for (int kt2 = 0; kt2 < 2; ++kt2) {
                    const int kt0 = k0 + wk*64 + (ks2*2 + kt2)*16;
                    const bool band = (unsigned)(qt0 - kt0 + 18) <= 36u;
                    float p[4];
                    if (band) {
                        #pragma unroll
                        for (int r = 0; r < 4; ++r) {
                            int dlt = (qt0 + l15) - (kt0 + quad*4 + r);
                            if (dlt < 0) dlt = -dlt;
                            p[r] = (dlt <= WIN_) ? 0.f
                                 : __builtin_amdgcn_exp2f(sacc[mt][kt2][r]);
                        }
                    } else {
                        #pragma unroll
                        for (int r = 0; r < 4; ++r)
                            p[r] = __builtin_amdgcn_exp2f(sacc[mt][kt2][r]);
                    }
                    dw[mt][kt2][0] = cvt_pk_bf16(p[0], p[1]);  // keys quad*4+{0,1}
                    dw[mt][kt2][1] = cvt_pk_bf16(p[2], p[3]);  // keys quad*4+{2,3}
                }
            }

            // ---- lane-swap P into PV A-frag: lane needs keys quad*8..+7 ----
            bf16x8 pa[2];
            #pragma unroll
            for (int mt = 0; mt < 2; ++mt) {
                uintx2 s0 = __builtin_amdgcn_permlane32_swap(
                    dw[mt][0][0], dw[mt][1][0], false, false);
                uintx2 a02 = __builtin_amdgcn_permlane16_swap(
                    s0.x, s0.y, false, false);
                uintx2 s1 = __builtin_amdgcn_permlane32_swap(
                    dw[mt][0][1], dw[mt][1][1], false, false);
                uintx2 a13 = __builtin_amdgcn_permlane16_swap(
                    s1.x, s1.y, false, false);
                union { unsigned int d[4]; bf16x8 v; } u;
                u.d[0] = a02.x;   // keys quad*8+{0,1}
                u.d[1] = a13.x;   // keys quad*8+{2,3}
                u.d[2] = a02.y;   // keys quad*8+{4,5}
                u.d[3] = a13.y;   // keys quad*8+{6,7}
                pa[mt] = u.v;
            }

            // ---- O += P V ; D += P 1 over this 32-key half ----
            __builtin_amdgcn_s_setprio(1);
            #pragma unroll
            for (int mt = 0; mt < 2; ++mt)
                Dacc[mt] = __builtin_amdgcn_mfma_f32_16x16x32_bf16(
                    pa[mt], ones, Dacc[mt], 0, 0, 0);
            #pragma unroll
            for (int nt = 0; nt < 4; ++nt)
                #pragma unroll
                for (int mt = 0; mt < 2; ++mt)
                    Oacc[mt][nt] = __builtin_amdgcn_mfma_f32_16x16x32_bf16(
                        pa[mt], vfc[nt], Oacc[mt][nt], 0, 0, 0);
            __builtin_amdgcn_s_setprio(0);
        }

        __syncthreads();   // all waves done with KV[cur]; next buffer's loads
                           // drained by the barrier's vmcnt(0)
        cur ^= 1;
    }

    // ---- merge key halves through LDS (Oex spans both K buffers; 32 KB) ----
    float* Oex = (float*)KV;             // 8192 floats = 32 KB
    if (wk == 1) {
        #pragma unroll
        for (int mt = 0; mt < 2; ++mt) {
            #pragma unroll
            for (int r = 0; r < 4; ++r) {
                const int qrow = wq*32 + mt*16 + quad*4 + r;
                Dex[qrow] = Dacc[mt][r];             // 16 lanes same value: benign
                #pragma unroll
                for (int nt = 0; nt < 4; ++nt)
                    Oex[qrow * 64 + nt*16 + l15] = Oacc[mt][nt][r];
            }
        }
    }
    __syncthreads();                     // Oex/Dex visible
    if (wk == 0) {
        const int b  = bh >> 4;
        const int hh = bh & 15;
        #pragma unroll
        for (int mt = 0; mt < 2; ++mt) {
            #pragma unroll
            for (int r = 0; r < 4; ++r) {
                const int qrow = wq*32 + mt*16 + quad*4 + r;
                const float iv = 1.f / (Dacc[mt][r] + Dex[qrow]);
                const int qg = q0 + qrow;
                float* op = out + (((size_t)b * S_ + qg) * H_ + hh) * D_;
                #pragma unroll
                for (int nt = 0; nt < 4; ++nt)
                    op[nt*16 + l15] =
                        (Oacc[mt][nt][r] + Oex[qrow * 64 + nt*16 + l15]) * iv;
            }
        }
    }
}

extern "C" void kernel_launch(void* const* d_in, const int* in_sizes, int n_in,
                              void* d_out, int out_size, void* d_ws, size_t ws_size,
                              hipStream_t stream) {
    const float* x  = (const float*)d_in[0];
    const float* Wq = (const float*)d_in[1];
    const float* bq = (const float*)d_in[2];
    const float* Wk = (const float*)d_in[3];
    const float* bk = (const float*)d_in[4];
    const float* Wv = (const float*)d_in[5];
    const float* bv = (const float*)d_in[6];
    float* out = (float*)d_out;

    const size_t per = (size_t)B_ * H_ * S_ * D_;   // 4,194,304 elements
    const size_t wsz = (size_t)E_ * E_;             // 1,048,576
    unsigned short* qb  = (unsigned short*)d_ws;
    unsigned short* kb  = qb + per;
    unsigned short* vb  = kb + per;
    unsigned short* xbf = vb + per;
    unsigned short* wqb = xbf + per;
    unsigned short* wkb = wqb + wsz;
    unsigned short* wvb = wkb + wsz;

    dim3 cgrid((B_ * S_ * E_ + 2047) / 2048, 4);
    cast_kernel<<<cgrid, 256, 0, stream>>>(x, Wq, Wk, Wv, xbf, wqb, wkb, wvb);

    dim3 ggrid(B_ * S_ / 128, E_ / 128, 3);
    gemm_kernel<<<ggrid, 256, 0, stream>>>(xbf, wqb, wkb, wvb, bq, bk, bv, qb, kb, vb);

    attn_kernel<<<dim3(512), 512, 0, stream>>>(qb, kb, vb, out);
}